// Round 9
// baseline (329.974 us; speedup 1.0000x reference)
//
#include <hip/hip_runtime.h>
#include <math.h>

// B=4, C=256, H=W=64, G=4, Cg=64, P=9. x [B,HW,C] is NHWC already.
// Convs via implicit-GEMM MFMA (bf16 2-term split: hi*hi + hi*lo + lo*hi).
// R9: INTERLEAVED hi/lo layout — activations [ch][b][4356 px][32hi|32lo]
// (128B per px per chunk), weights [ch][tap][OCPAD][32hi|32lo]. Ah/Al share
// cache lines (lo is an MSHR/L1 hit behind hi); prep/epilogue writes are
// 128B-contiguous. All prep work (acc zerofill + halo ring + x transform +
// weight transform) merged into ONE dispatch.
// Learned R8: fp32 atomicAdd is memory-side on gfx950 (full EA write traffic
// even to L2-resident buffers) — atomics kept only where block-count needs it.

typedef __attribute__((ext_vector_type(8))) short short8;
typedef __attribute__((ext_vector_type(4))) float floatx4;

__device__ __forceinline__ unsigned short f2bf(float f) {
    unsigned u = __float_as_uint(f);
    u = (u + 0x7FFFu + ((u >> 16) & 1u)) >> 16;
    return (unsigned short)u;
}
__device__ __forceinline__ float bf2f(unsigned short h) {
    return __uint_as_float(((unsigned)h) << 16);
}
__device__ __forceinline__ float gelu_exact(float v) {
    return 0.5f * v * (1.0f + erff(v * 0.70710678118654752f));
}

// ---------------- MFMA implicit-GEMM conv core (interleaved chunked layout) --------
// Activations: [ch][b][4356 px][64] ushort: [0,32)=hi, [32,64)=lo of 32 ic.
// Weights: [ch][tap][OCPAD][64] ushort, same hi/lo split.
// Wave tile: 32 px x NT*16 oc. Block = 4 waves = 128 consecutive px (2 rows).
// A frag: m=lane&15 -> pixel, k=quad*8+j -> ic. B frag: n=lane&15 -> oc.
// C/D: col(oc)=lane&15, row(pixel)=quad*4+reg.
// ACT: 0 none, 1 gelu(exact), 2 sigmoid.
// OUTMODE: 1 interleaved split-bf16 out (bias+act), 2 fp32 atomicAdd partial.
template<int NC, int MT, int NT, int ACT, int OUTMODE>
__device__ __forceinline__ void conv_core(
    const unsigned short* __restrict__ ax, int aC0,
    const unsigned short* __restrict__ wx,
    const float* __restrict__ bias,
    int b, int mblock, int tap0, int ntaps,
    unsigned short* __restrict__ ox, int oC0,
    float* __restrict__ pf)
{
    const int OCPAD = NT * 16;
    int wave = threadIdx.x >> 6;
    int lane = threadIdx.x & 63;
    int quad = lane >> 4;
    int l16 = lane & 15;

    int pix0 = (mblock * 4 + wave) * (MT * 16);   // [0,4096)
    int y = pix0 >> 6;
    int x0 = pix0 & 63;

    floatx4 acc[MT][NT];
#pragma unroll
    for (int nt = 0; nt < NT; nt++) {
        float bv = (OUTMODE == 1) ? bias[nt * 16 + l16] : 0.f;
#pragma unroll
        for (int mt = 0; mt < MT; mt++) { floatx4 v = {bv, bv, bv, bv}; acc[mt][nt] = v; }
    }

    const int TOTAL = ntaps * NC;
    short8 Ah[2][MT], Al[2][MT], Bh[2][NT], Bl[2][NT];

    auto load_frag = [&](int slot, int it) {
        int tap = tap0 + it / NC;
        int ch = it % NC;
        int kh = tap / 3, kw = tap - kh * 3;
        // A: px unit = 128B (32 hi + 32 lo); Ah/Al from the same lines
        size_t r = ((size_t)((aC0 + ch) * 4 + b) * 4356 + (y + kh) * 66 + (x0 + kw) + l16) * 64 + quad * 8;
#pragma unroll
        for (int mt = 0; mt < MT; mt++) {
            Ah[slot][mt] = *(const short8*)(ax + r + (size_t)(mt * 16) * 64);
            Al[slot][mt] = *(const short8*)(ax + r + (size_t)(mt * 16) * 64 + 32);
        }
        size_t wr = ((size_t)(ch * 9 + tap) * OCPAD + l16) * 64 + quad * 8;
#pragma unroll
        for (int nt = 0; nt < NT; nt++) {
            Bh[slot][nt] = *(const short8*)(wx + wr + (size_t)(nt * 16) * 64);
            Bl[slot][nt] = *(const short8*)(wx + wr + (size_t)(nt * 16) * 64 + 32);
        }
    };

    load_frag(0, 0);
#pragma unroll 2
    for (int it = 0; it < TOTAL; it++) {
        int cur = it & 1, nxt = cur ^ 1;
        if (it + 1 < TOTAL) load_frag(nxt, it + 1);
#pragma unroll
        for (int nt = 0; nt < NT; nt++) {
#pragma unroll
            for (int mt = 0; mt < MT; mt++) {
                acc[mt][nt] = __builtin_amdgcn_mfma_f32_16x16x32_bf16(Ah[cur][mt], Bh[cur][nt], acc[mt][nt], 0, 0, 0);
                acc[mt][nt] = __builtin_amdgcn_mfma_f32_16x16x32_bf16(Ah[cur][mt], Bl[cur][nt], acc[mt][nt], 0, 0, 0);
                acc[mt][nt] = __builtin_amdgcn_mfma_f32_16x16x32_bf16(Al[cur][mt], Bh[cur][nt], acc[mt][nt], 0, 0, 0);
            }
        }
    }

#pragma unroll
    for (int nt = 0; nt < NT; nt++) {
        int oc = nt * 16 + l16;
#pragma unroll
        for (int mt = 0; mt < MT; mt++) {
#pragma unroll
            for (int r = 0; r < 4; r++) {
                float v = acc[mt][nt][r];
                int px = pix0 + mt * 16 + quad * 4 + r;
                if (OUTMODE == 2) {
                    atomicAdd(pf + ((size_t)b * 4096 + px) * OCPAD + oc, v);
                } else {
                    if (ACT == 1) v = gelu_exact(v);
                    else if (ACT == 2) v = 1.0f / (1.0f + expf(-v));
                    int yy = (px >> 6) + 1, xx = (px & 63) + 1;
                    int och = oC0 + (oc >> 5);
                    size_t o = ((size_t)(och * 4 + b) * 4356 + yy * 66 + xx) * 64 + (oc & 31);
                    unsigned short hv = f2bf(v);
                    ox[o] = hv;
                    ox[o + 32] = f2bf(v - bf2f(hv));
                }
            }
        }
    }
}

// convA: conv1 (grouped C->C, gelu, direct ->h1) + conv3 (256->64, K-split x6 -> P3 atomics)
// grid.x = 320: [0,128): conv1 (g=bx>>5, mb=bx&31, 18 iters)
//               [128,320): conv3: ks=(bx-128)>>5 in [0,6), mb=&31, 12 iters
__global__ __launch_bounds__(256, 2) void convA_kernel(
    const unsigned short* __restrict__ xp,
    const unsigned short* __restrict__ w1,
    const float* __restrict__ off_b1,
    const unsigned short* __restrict__ w3,
    unsigned short* __restrict__ h1,
    float* __restrict__ P3)
{
    int b = blockIdx.z;
    int bx = blockIdx.x;
    if (bx < 128) {
        int g = bx >> 5;
        int mb = bx & 31;
        conv_core<2, 2, 4, 1, 1>(xp, g * 2,
            w1 + (size_t)g * 2 * 9 * 64 * 64, off_b1 + g * 64,
            b, mb, 0, 9, h1, g * 2, nullptr);
    } else {
        int t = bx - 128;
        int ks = t >> 5;           // 0..5
        int mb = t & 31;
        int ks_c = ks & 1;         // chunk half: chunks 0-3 / 4-7
        int ks_t = ks >> 1;        // tap group: 0..2
        conv_core<4, 2, 4, 0, 2>(xp, ks_c * 4,
            w3 + (size_t)(ks_c * 4) * 9 * 64 * 64, nullptr,
            b, mb, ks_t * 3, 3, nullptr, 0, P3);
    }
}

// finalizeA: m1 = gelu(P3 + mod_b1) -> interleaved split-bf16.
__global__ __launch_bounds__(256) void finalizeA_kernel(
    const float* __restrict__ P3, const float* __restrict__ mod_b1,
    unsigned short* __restrict__ m1)
{
    int idx = blockIdx.x * 256 + threadIdx.x;   // (b*4096+px)*64 + c
    int c = idx & 63;
    int p = idx >> 6;            // b*4096+px
    int b = p >> 12;
    int px = p & 4095;
    int rem = ((px >> 6) + 1) * 66 + (px & 63) + 1;
    float u = P3[(size_t)p * 64 + c] + mod_b1[c];
    u = gelu_exact(u);
    size_t o = ((size_t)((c >> 5) * 4 + b) * 4356 + rem) * 64 + (c & 31);
    unsigned short hu = f2bf(u);
    m1[o] = hu;
    m1[o + 32] = f2bf(u - bf2f(hu));
}

// convB: conv2 (256->80pad, K-split x6 -> P2a atomics) + conv4 (64->48pad, x3 -> P4a)
// grid.x = 288: [0,192): conv2 (ks=bx>>5 in [0,6), mb=bx&31)
//               [192,288): conv4 (ks=(bx-192)>>5 in [0,3), mb=&31)
__global__ __launch_bounds__(256, 2) void convB_kernel(
    const unsigned short* __restrict__ h1,
    const unsigned short* __restrict__ w2,
    const unsigned short* __restrict__ m1,
    const unsigned short* __restrict__ w4,
    float* __restrict__ P2a, float* __restrict__ P4a)
{
    int b = blockIdx.z;
    int bx = blockIdx.x;
    if (bx < 192) {
        int ks = bx >> 5;          // 0..5
        int mb = bx & 31;
        int ks_c = ks & 1;
        int ks_t = ks >> 1;
        conv_core<4, 2, 5, 0, 2>(h1, ks_c * 4,
            w2 + (size_t)(ks_c * 4) * 9 * 80 * 64, nullptr,
            b, mb, ks_t * 3, 3, nullptr, 0, P2a);
    } else {
        int t = bx - 192;
        int ks = t >> 5;           // 0..2
        int mb = t & 31;
        conv_core<2, 2, 3, 0, 2>(m1, 0, w4, nullptr,
            b, mb, ks * 3, 3, nullptr, 0, P4a);
    }
}

// ---------------- merged prep kernel ----------------
// One dispatch: [0,ZBLK) zero accumulators; [+RBLK) halo ring zero;
// [+XBLK) x -> interleaved split-bf16; [+WBLK) weights -> interleaved.
#define ZBLK 3072   // 3,145,728 floats = 786,432 uint4 / 256
#define RBLK 1040   // 4*260 ring px
#define XBLK 17424  // 4*4356
#define WBLK 3960   // 1,013,760 weight ushorts / 256
__global__ void prep_all_kernel(
    const float* __restrict__ x,
    const float* __restrict__ w1f, const float* __restrict__ w2f,
    const float* __restrict__ w3f, const float* __restrict__ w4f,
    unsigned short* __restrict__ xp,
    unsigned short* __restrict__ h1, unsigned short* __restrict__ m1,
    unsigned short* __restrict__ w1, unsigned short* __restrict__ w2,
    unsigned short* __restrict__ w3, unsigned short* __restrict__ w4,
    float* __restrict__ accf)
{
    int blk = blockIdx.x;
    int t = threadIdx.x;
    if (blk < ZBLK) {
        ((uint4*)accf)[(size_t)blk * 256 + t] = make_uint4(0u, 0u, 0u, 0u);
        return;
    }
    blk -= ZBLK;
    if (blk < RBLK) {
        int b = blk / 260;
        int r = blk - b * 260;
        int i, j;
        if (r < 66)       { i = 0;        j = r; }
        else if (r < 132) { i = 65;       j = r - 66; }
        else if (r < 196) { i = r - 131;  j = 0; }     // rows 1..64
        else              { i = r - 195;  j = 65; }
        size_t pp = (size_t)i * 66 + j;
        int ch = t >> 5, sub = t & 31;
        size_t o = ((size_t)(ch * 4 + b) * 4356 + pp) * 64 + sub;
        h1[o] = 0; h1[o + 32] = 0;
        if (t < 128) { m1[o] = 0; m1[o + 32] = 0; }   // ch<2
        return;
    }
    blk -= RBLK;
    if (blk < XBLK) {
        int b = blk / 4356;
        int rem = blk - b * 4356;
        int i = rem / 66, j = rem - i * 66;
        float v = 0.f;
        if (i >= 1 && i <= 64 && j >= 1 && j <= 64)
            v = x[((size_t)b * 4096 + (size_t)(i - 1) * 64 + (j - 1)) * 256 + t];
        size_t o = ((size_t)((t >> 5) * 4 + b) * 4356 + rem) * 64 + (t & 31);
        unsigned short h = f2bf(v);
        xp[o] = h;
        xp[o + 32] = f2bf(v - bf2f(h));
        return;
    }
    blk -= XBLK;
    {
        const int N1 = 294912, N2 = 368640, N3 = 294912, N4 = 55296;
        int idx = blk * 256 + t;
        const float* w; unsigned short* outp;
        int ocpad, oc_real, ic, base;
        if (idx < N1)                { w = w1f; outp = w1; ocpad = 64; oc_real = 64; ic = 64;  base = 0; }
        else if (idx < N1 + N2)      { w = w2f; outp = w2; ocpad = 80; oc_real = 72; ic = 256; base = N1; }
        else if (idx < N1 + N2 + N3) { w = w3f; outp = w3; ocpad = 64; oc_real = 64; ic = 256; base = N1 + N2; }
        else                         { w = w4f; outp = w4; ocpad = 48; oc_real = 36; ic = 64;  base = N1 + N2 + N3; }
        int lidx = idx - base;
        // lidx -> [g][ch][tap][ocp][slot64], slot<32: hi of ic, slot>=32: lo
        int slot = lidx & 63;
        int ici = slot & 31;
        int is_lo = slot >> 5;
        int t1 = lidx >> 6;
        int ocp = t1 % ocpad;
        int t2 = t1 / ocpad;
        int tap = t2 % 9;
        int t3 = t2 / 9;
        int nch = ic >> 5;
        int ch = t3 % nch;
        int g = t3 / nch;
        float v = 0.f;
        if (ocp < oc_real) {
            int oc = g * oc_real + ocp;
            int icx = ch * 32 + ici;
            v = w[((size_t)oc * ic + icx) * 9 + tap];
        }
        unsigned short h = f2bf(v);
        outp[lidx] = is_lo ? f2bf(v - bf2f(h)) : h;
    }
}

// ---------------- deformable sampling (exact fp32, finalizeB fused) ----------------
// 4 points per wave, 16 lanes per point, float4 gathers (4 channels/lane).
// Reads raw conv partials P2a/P4a and applies bias / sigmoid inline.
__global__ __launch_bounds__(256) void deform_sample(
    const float* __restrict__ x,
    const float* __restrict__ P2a, const float* __restrict__ P4a,
    const float* __restrict__ b2, const float* __restrict__ b4,
    float* __restrict__ out)
{
    int wid = (int)((blockIdx.x * 256u + threadIdx.x) >> 6);   // 0..16383
    int lane = (int)(threadIdx.x & 63u);
    int sub = lane >> 4;         // 0..3: which point
    int li = lane & 15;

    int b = wid >> 12;           // 4096 waves per batch
    int rem = wid & 4095;
    int g = rem >> 10;
    int hw = ((rem & 1023) << 2) + sub;
    int hy = hw >> 6;
    int wx = hw & 63;

    // lanes li<9 of each subwave: offsets (P2a+b2) and modulation sigmoid(P4a+b4)
    float fx = 0.f, fy = 0.f, fm = 0.f;
    if (li < 9) {
        size_t p = (size_t)(b << 12) + hw;
        int c2 = g * 18 + li;
        fx = P2a[p * 80 + c2] + b2[c2];
        fy = P2a[p * 80 + 9 + c2] + b2[9 + c2];
        int c4 = g * 9 + li;
        float mv = P4a[p * 48 + c4] + b4[c4];
        fm = 1.0f / (1.0f + expf(-mv));
    }
    float px = fminf(fmaxf((float)wx + (float)(li % 3 - 1) + fx, 0.f), 63.f);
    float py = fminf(fmaxf((float)hy + (float)(li / 3 - 1) + fy, 0.f), 63.f);
    float x0f = floorf(px), y0f = floorf(py);
    float wxf = px - x0f, wyf = py - y0f;
    int x0 = (int)x0f, y0 = (int)y0f;
    int x1 = min(x0 + 1, 63), y1 = min(y0 + 1, 63);

    // lane li gathers channels g*64 + li*4 .. +3 as float4
    const float4* xb = (const float4*)(x + ((size_t)(b << 12)) * 256 + g * 64 + li * 4);
    float4 acc = make_float4(0.f, 0.f, 0.f, 0.f);
    int sb = sub << 4;
#pragma unroll
    for (int q = 0; q < 9; q++) {
        int src = sb + q;
        int   qx0 = __shfl(x0, src);
        int   qx1 = __shfl(x1, src);
        int   qy0 = __shfl(y0, src);
        int   qy1 = __shfl(y1, src);
        float qwx = __shfl(wxf, src);
        float qwy = __shfl(wyf, src);
        float qm  = __shfl(fm, src);
        float4 v00 = xb[(size_t)(qy0 * 64 + qx0) * 64];
        float4 v01 = xb[(size_t)(qy0 * 64 + qx1) * 64];
        float4 v10 = xb[(size_t)(qy1 * 64 + qx0) * 64];
        float4 v11 = xb[(size_t)(qy1 * 64 + qx1) * 64];
        float w00 = (1.f - qwx) * (1.f - qwy);
        float w01 = qwx * (1.f - qwy);
        float w10 = (1.f - qwx) * qwy;
        float w11 = qwx * qwy;
        acc.x += qm * (v00.x * w00 + v01.x * w01 + v10.x * w10 + v11.x * w11);
        acc.y += qm * (v00.y * w00 + v01.y * w01 + v10.y * w10 + v11.y * w11);
        acc.z += qm * (v00.z * w00 + v01.z * w01 + v10.z * w10 + v11.z * w11);
        acc.w += qm * (v00.w * w00 + v01.w * w01 + v10.w * w10 + v11.w * w11);
    }
    const float s = 1.f / 9.f;
    acc.x *= s; acc.y *= s; acc.z *= s; acc.w *= s;
    float4* ob = (float4*)(out + ((size_t)(b << 12) + hw) * 256 + g * 64 + li * 4);
    *ob = acc;
}

extern "C" void kernel_launch(void* const* d_in, const int* in_sizes, int n_in,
                              void* d_out, int out_size, void* d_ws, size_t ws_size,
                              hipStream_t stream)
{
    const float* x      = (const float*)d_in[0];
    const float* off_w1 = (const float*)d_in[1];
    const float* off_b1 = (const float*)d_in[2];
    const float* off_w2 = (const float*)d_in[3];
    const float* off_b2 = (const float*)d_in[4];
    const float* mod_w1 = (const float*)d_in[5];
    const float* mod_b1 = (const float*)d_in[6];
    const float* mod_w2 = (const float*)d_in[7];
    const float* mod_b2 = (const float*)d_in[8];

    // ws layout (ushort units; interleaved hi/lo, 128B px units)
    const size_t XP2 = 8u * 4u * 4356u * 64u;     // 8,921,088 x interleaved
    const size_t M2  = 2u * 4u * 4356u * 64u;     // 2,230,272
    const size_t W1s = 4u * 2u * 9u * 64u * 64u;  // 294,912
    const size_t W2s = 8u * 9u * 80u * 64u;       // 368,640
    const size_t W3s = 8u * 9u * 64u * 64u;       // 294,912
    const size_t W4s = 2u * 9u * 48u * 64u;       // 55,296

    unsigned short* ws = (unsigned short*)d_ws;
    size_t o = 0;
    unsigned short* xp = ws + o; o += XP2;
    unsigned short* h1 = ws + o; o += XP2;
    unsigned short* m1 = ws + o; o += M2;
    unsigned short* w1 = ws + o; o += W1s;
    unsigned short* w2 = ws + o; o += W2s;
    unsigned short* w3 = ws + o; o += W3s;
    unsigned short* w4 = ws + o; o += W4s;
    // fp32 accumulators, contiguous (zeroed by prep seg 0):
    float* fbase = (float*)(ws + o);
    float* P3  = fbase;                              // [4*4096][64]
    float* P2a = P3 + (size_t)4 * 4096 * 64;         // [4*4096][80]
    float* P4a = P2a + (size_t)4 * 4096 * 80;        // [4*4096][48]
    const size_t ACC_FLOATS = (size_t)4 * 4096 * (64 + 80 + 48);  // 3,145,728
    size_t need_bytes = o * 2 + ACC_FLOATS * 4;      // ~55 MB (ws ~268 MB)
    if (ws_size < need_bytes) return;  // deterministic guard

    prep_all_kernel<<<ZBLK + RBLK + XBLK + WBLK, 256, 0, stream>>>(
        x, off_w1, off_w2, mod_w1, mod_w2,
        xp, h1, m1, w1, w2, w3, w4, P3);

    convA_kernel<<<dim3(320, 1, 4), 256, 0, stream>>>(xp, w1, off_b1, w3, h1, P3);
    finalizeA_kernel<<<4096, 256, 0, stream>>>(P3, mod_b1, m1);
    convB_kernel<<<dim3(288, 1, 4), 256, 0, stream>>>(h1, w2, m1, w4, P2a, P4a);
    deform_sample<<<4096, 256, 0, stream>>>(x, P2a, P4a, off_b2, mod_b2, (float*)d_out);
}

// Round 10
// 239.026 us; speedup vs baseline: 1.3805x; 1.3805x over previous
//
#include <hip/hip_runtime.h>
#include <math.h>

// B=4, C=256, H=W=64, G=4, Cg=64, P=9. x [B,HW,C] is NHWC already.
// Convs via implicit-GEMM MFMA (bf16 2-term split: hi*hi + hi*lo + lo*hi).
// Chunked SPLIT-ARRAY layout (R5/R8, proven): activations [ch][b][4356 px][32]
// in separate hi/lo arrays -> every A/B fragment load is 1KB contiguous.
// R9's interleaved layout REGRESSED (128B-strided loads) — reverted.
// R10: merged prep kept; atomic-write tax cut per R8 lesson (fp32 atomicAdd
// is memory-side on gfx950): conv3 ksplit x6->x3, conv2 x6->x3, conv4
// un-split with plain fp32 stores (no atomics, no zero-init).

typedef __attribute__((ext_vector_type(8))) short short8;
typedef __attribute__((ext_vector_type(4))) float floatx4;

__device__ __forceinline__ unsigned short f2bf(float f) {
    unsigned u = __float_as_uint(f);
    u = (u + 0x7FFFu + ((u >> 16) & 1u)) >> 16;
    return (unsigned short)u;
}
__device__ __forceinline__ float bf2f(unsigned short h) {
    return __uint_as_float(((unsigned)h) << 16);
}
__device__ __forceinline__ void split2(float v, unsigned short* hi, unsigned short* lo) {
    unsigned short h = f2bf(v);
    *hi = h;
    *lo = f2bf(v - bf2f(h));
}
__device__ __forceinline__ float gelu_exact(float v) {
    return 0.5f * v * (1.0f + erff(v * 0.70710678118654752f));
}

// ---------------- MFMA implicit-GEMM conv core (chunked split layout) ----------
// Activations: [ch][b][4356 px][32] ushort (hi/lo arrays). px = y*66+x, padded.
// Weights: [ch][tap][OCPAD][32] ushort (hi/lo arrays).
// Wave tile: 32 px x NT*16 oc. Block = 4 waves = 128 consecutive px (2 rows).
// A frag: m=lane&15 -> pixel, k=quad*8+j -> ic. B frag: n=lane&15 -> oc.
// C/D: col(oc)=lane&15, row(pixel)=quad*4+reg.
// ACT: 0 none, 1 gelu(exact), 2 sigmoid.
// OUTMODE: 1 split-bf16 out (bias+act), 2 fp32 atomicAdd partial,
//          3 fp32 plain store (row stride OCPAD, block owns its pixels).
template<int NC, int MT, int NT, int ACT, int OUTMODE>
__device__ __forceinline__ void conv_core(
    const unsigned short* __restrict__ ah, const unsigned short* __restrict__ al,
    int aC0,
    const unsigned short* __restrict__ wh, const unsigned short* __restrict__ wl,
    const float* __restrict__ bias,
    int b, int mblock, int tap0, int ntaps,
    unsigned short* __restrict__ oh, unsigned short* __restrict__ ol,
    int oC0,
    float* __restrict__ pf)
{
    const int OCPAD = NT * 16;
    int wave = threadIdx.x >> 6;
    int lane = threadIdx.x & 63;
    int quad = lane >> 4;
    int l16 = lane & 15;

    int pix0 = (mblock * 4 + wave) * (MT * 16);   // [0,4096)
    int y = pix0 >> 6;
    int x0 = pix0 & 63;

    floatx4 acc[MT][NT];
#pragma unroll
    for (int nt = 0; nt < NT; nt++) {
        float bv = (OUTMODE == 1) ? bias[nt * 16 + l16] : 0.f;
#pragma unroll
        for (int mt = 0; mt < MT; mt++) { floatx4 v = {bv, bv, bv, bv}; acc[mt][nt] = v; }
    }

    const int TOTAL = ntaps * NC;
    short8 Ah[2][MT], Al[2][MT], Bh[2][NT], Bl[2][NT];

    auto load_frag = [&](int slot, int it) {
        int tap = tap0 + it / NC;
        int ch = it % NC;
        int kh = tap / 3, kw = tap - kh * 3;
        // A: contiguous 1KB per instruction: pixel stride = 32 ushorts = 64B
        size_t r = ((size_t)((aC0 + ch) * 4 + b) * 4356 + (y + kh) * 66 + (x0 + kw) + l16) * 32 + quad * 8;
#pragma unroll
        for (int mt = 0; mt < MT; mt++) {
            Ah[slot][mt] = *(const short8*)(ah + r + (size_t)(mt * 16) * 32);
            Al[slot][mt] = *(const short8*)(al + r + (size_t)(mt * 16) * 32);
        }
        // B: contiguous 1KB per instruction: oc stride = 32 ushorts = 64B
        size_t wr = ((size_t)(ch * 9 + tap) * OCPAD + l16) * 32 + quad * 8;
#pragma unroll
        for (int nt = 0; nt < NT; nt++) {
            Bh[slot][nt] = *(const short8*)(wh + wr + (size_t)(nt * 16) * 32);
            Bl[slot][nt] = *(const short8*)(wl + wr + (size_t)(nt * 16) * 32);
        }
    };

    load_frag(0, 0);
#pragma unroll 2
    for (int it = 0; it < TOTAL; it++) {
        int cur = it & 1, nxt = cur ^ 1;
        if (it + 1 < TOTAL) load_frag(nxt, it + 1);
#pragma unroll
        for (int nt = 0; nt < NT; nt++) {
#pragma unroll
            for (int mt = 0; mt < MT; mt++) {
                acc[mt][nt] = __builtin_amdgcn_mfma_f32_16x16x32_bf16(Ah[cur][mt], Bh[cur][nt], acc[mt][nt], 0, 0, 0);
                acc[mt][nt] = __builtin_amdgcn_mfma_f32_16x16x32_bf16(Ah[cur][mt], Bl[cur][nt], acc[mt][nt], 0, 0, 0);
                acc[mt][nt] = __builtin_amdgcn_mfma_f32_16x16x32_bf16(Al[cur][mt], Bh[cur][nt], acc[mt][nt], 0, 0, 0);
            }
        }
    }

#pragma unroll
    for (int nt = 0; nt < NT; nt++) {
        int oc = nt * 16 + l16;
#pragma unroll
        for (int mt = 0; mt < MT; mt++) {
#pragma unroll
            for (int r = 0; r < 4; r++) {
                float v = acc[mt][nt][r];
                int px = pix0 + mt * 16 + quad * 4 + r;
                if (OUTMODE == 2) {
                    atomicAdd(pf + ((size_t)b * 4096 + px) * OCPAD + oc, v);
                } else if (OUTMODE == 3) {
                    pf[((size_t)b * 4096 + px) * OCPAD + oc] = v;
                } else {
                    if (ACT == 1) v = gelu_exact(v);
                    else if (ACT == 2) v = 1.0f / (1.0f + expf(-v));
                    int yy = (px >> 6) + 1, xx = (px & 63) + 1;
                    int och = oC0 + (oc >> 5);
                    size_t o = ((size_t)(och * 4 + b) * 4356 + yy * 66 + xx) * 32 + (oc & 31);
                    unsigned short hv, lv; split2(v, &hv, &lv);
                    oh[o] = hv; ol[o] = lv;
                }
            }
        }
    }
}

// convA: conv1 (grouped C->C, gelu, direct ->h1pad) + conv3 (256->64, K-split x3 taps -> P3 atomics)
// grid.x = 224: [0,128): conv1 (g=bx>>5, mb=bx&31, 18 iters)
//               [128,224): conv3: ks=(bx-128)>>5 in [0,3), mb=&31, 24 iters
__global__ __launch_bounds__(256, 2) void convA_kernel(
    const unsigned short* __restrict__ xph, const unsigned short* __restrict__ xpl,
    const unsigned short* __restrict__ w1h, const unsigned short* __restrict__ w1l,
    const float* __restrict__ off_b1,
    const unsigned short* __restrict__ w3h, const unsigned short* __restrict__ w3l,
    unsigned short* __restrict__ h1h, unsigned short* __restrict__ h1l,
    float* __restrict__ P3)
{
    int b = blockIdx.z;
    int bx = blockIdx.x;
    if (bx < 128) {
        int g = bx >> 5;
        int mb = bx & 31;
        conv_core<2, 2, 4, 1, 1>(xph, xpl, g * 2,
            w1h + (size_t)g * 2 * 9 * 64 * 32, w1l + (size_t)g * 2 * 9 * 64 * 32,
            off_b1 + g * 64,
            b, mb, 0, 9, h1h, h1l, g * 2, nullptr);
    } else {
        int t = bx - 128;
        int ks = t >> 5;           // 0..2 tap groups
        int mb = t & 31;
        conv_core<8, 2, 4, 0, 2>(xph, xpl, 0, w3h, w3l, nullptr,
            b, mb, ks * 3, 3, nullptr, nullptr, 0, P3);
    }
}

// finalizeA: m1 = gelu(P3 + mod_b1) -> split-bf16.
__global__ __launch_bounds__(256) void finalizeA_kernel(
    const float* __restrict__ P3, const float* __restrict__ mod_b1,
    unsigned short* __restrict__ m1h, unsigned short* __restrict__ m1l)
{
    int idx = blockIdx.x * 256 + threadIdx.x;   // (b*4096+px)*64 + c
    int c = idx & 63;
    int p = idx >> 6;            // b*4096+px
    int b = p >> 12;
    int px = p & 4095;
    int rem = ((px >> 6) + 1) * 66 + (px & 63) + 1;
    float u = P3[(size_t)p * 64 + c] + mod_b1[c];
    u = gelu_exact(u);
    size_t o = ((size_t)((c >> 5) * 4 + b) * 4356 + rem) * 32 + (c & 31);
    unsigned short hu, lu; split2(u, &hu, &lu);
    m1h[o] = hu; m1l[o] = lu;
}

// convB: conv2 (256->80pad, K-split x3 taps -> P2a atomics) + conv4 (64->48pad, un-split, plain stores)
// grid.x = 128: [0,96): conv2 (ks=bx>>5 in [0,3), mb=bx&31, 24 iters)
//               [96,128): conv4 (mb=bx-96, 18 iters, direct P4a)
__global__ __launch_bounds__(256, 2) void convB_kernel(
    const unsigned short* __restrict__ h1h, const unsigned short* __restrict__ h1l,
    const unsigned short* __restrict__ w2h, const unsigned short* __restrict__ w2l,
    const unsigned short* __restrict__ m1h, const unsigned short* __restrict__ m1l,
    const unsigned short* __restrict__ w4h, const unsigned short* __restrict__ w4l,
    float* __restrict__ P2a, float* __restrict__ P4a)
{
    int b = blockIdx.z;
    int bx = blockIdx.x;
    if (bx < 96) {
        int ks = bx >> 5;          // 0..2 tap groups
        int mb = bx & 31;
        conv_core<8, 2, 5, 0, 2>(h1h, h1l, 0, w2h, w2l, nullptr,
            b, mb, ks * 3, 3, nullptr, nullptr, 0, P2a);
    } else {
        int mb = bx - 96;
        conv_core<2, 2, 3, 0, 3>(m1h, m1l, 0, w4h, w4l, nullptr,
            b, mb, 0, 9, nullptr, nullptr, 0, P4a);
    }
}

// ---------------- merged prep kernel (one dispatch) ----------------
// [0,ZBLK): zero P3+P2a accumulators; [+RBLK): halo ring zero;
// [+XBLK): x -> split-bf16 chunked; [+WBLK): weights -> split-bf16.
#define ZBLK 2304   // (4*4096*(64+80)) floats = 589,824 uint4 / 256
#define RBLK 1040   // 4*260 ring px
#define XBLK 17424  // 4*4356
#define WBLK 1980   // 506,880 weight elements / 256
__global__ void prep_all_kernel(
    const float* __restrict__ x,
    const float* __restrict__ w1f, const float* __restrict__ w2f,
    const float* __restrict__ w3f, const float* __restrict__ w4f,
    unsigned short* __restrict__ xph, unsigned short* __restrict__ xpl,
    unsigned short* __restrict__ h1h, unsigned short* __restrict__ h1l,
    unsigned short* __restrict__ m1h, unsigned short* __restrict__ m1l,
    unsigned short* __restrict__ w1h, unsigned short* __restrict__ w1l,
    unsigned short* __restrict__ w2h, unsigned short* __restrict__ w2l,
    unsigned short* __restrict__ w3h, unsigned short* __restrict__ w3l,
    unsigned short* __restrict__ w4h, unsigned short* __restrict__ w4l,
    float* __restrict__ accf)
{
    int blk = blockIdx.x;
    int t = threadIdx.x;
    if (blk < ZBLK) {
        ((uint4*)accf)[(size_t)blk * 256 + t] = make_uint4(0u, 0u, 0u, 0u);
        return;
    }
    blk -= ZBLK;
    if (blk < RBLK) {
        int b = blk / 260;
        int r = blk - b * 260;
        int i, j;
        if (r < 66)       { i = 0;        j = r; }
        else if (r < 132) { i = 65;       j = r - 66; }
        else if (r < 196) { i = r - 131;  j = 0; }     // rows 1..64
        else              { i = r - 195;  j = 65; }
        size_t pp = (size_t)i * 66 + j;
        int ch = t >> 5, sub = t & 31;
        size_t o = ((size_t)(ch * 4 + b) * 4356 + pp) * 32 + sub;
        h1h[o] = 0; h1l[o] = 0;
        if (t < 64) { m1h[o] = 0; m1l[o] = 0; }
        return;
    }
    blk -= RBLK;
    if (blk < XBLK) {
        int b = blk / 4356;
        int rem = blk - b * 4356;
        int i = rem / 66, j = rem - i * 66;
        float v = 0.f;
        if (i >= 1 && i <= 64 && j >= 1 && j <= 64)
            v = x[((size_t)b * 4096 + (size_t)(i - 1) * 64 + (j - 1)) * 256 + t];
        size_t o = ((size_t)((t >> 5) * 4 + b) * 4356 + rem) * 32 + (t & 31);
        unsigned short h, l; split2(v, &h, &l);
        xph[o] = h; xpl[o] = l;
        return;
    }
    blk -= XBLK;
    {
        const int N1 = 147456, N2 = 184320, N3 = 147456, N4 = 27648;
        int idx = blk * 256 + t;
        const float* w; unsigned short *outh, *outl;
        int ocpad, oc_real, ic, base;
        if (idx < N1)                { w = w1f; outh = w1h; outl = w1l; ocpad = 64; oc_real = 64; ic = 64;  base = 0; }
        else if (idx < N1 + N2)      { w = w2f; outh = w2h; outl = w2l; ocpad = 80; oc_real = 72; ic = 256; base = N1; }
        else if (idx < N1 + N2 + N3) { w = w3f; outh = w3h; outl = w3l; ocpad = 64; oc_real = 64; ic = 256; base = N1 + N2; }
        else                         { w = w4f; outh = w4h; outl = w4l; ocpad = 48; oc_real = 36; ic = 64;  base = N1 + N2 + N3; }
        int lidx = idx - base;
        // lidx -> [g][ch][tap][ocp][ici]
        int ici = lidx & 31;
        int t1 = lidx >> 5;
        int ocp = t1 % ocpad;
        int t2 = t1 / ocpad;
        int tap = t2 % 9;
        int t3 = t2 / 9;
        int nch = ic >> 5;
        int ch = t3 % nch;
        int g = t3 / nch;
        float v = 0.f;
        if (ocp < oc_real) {
            int oc = g * oc_real + ocp;
            int icx = ch * 32 + ici;
            v = w[((size_t)oc * ic + icx) * 9 + tap];
        }
        unsigned short h, l; split2(v, &h, &l);
        outh[lidx] = h; outl[lidx] = l;
    }
}

// ---------------- deformable sampling (exact fp32, finalizeB fused) ----------------
// 4 points per wave, 16 lanes per point, float4 gathers (4 channels/lane).
// Reads raw conv partials P2a/P4a and applies bias / sigmoid inline.
__global__ __launch_bounds__(256) void deform_sample(
    const float* __restrict__ x,
    const float* __restrict__ P2a, const float* __restrict__ P4a,
    const float* __restrict__ b2, const float* __restrict__ b4,
    float* __restrict__ out)
{
    int wid = (int)((blockIdx.x * 256u + threadIdx.x) >> 6);   // 0..16383
    int lane = (int)(threadIdx.x & 63u);
    int sub = lane >> 4;         // 0..3: which point
    int li = lane & 15;

    int b = wid >> 12;           // 4096 waves per batch
    int rem = wid & 4095;
    int g = rem >> 10;
    int hw = ((rem & 1023) << 2) + sub;
    int hy = hw >> 6;
    int wx = hw & 63;

    // lanes li<9 of each subwave: offsets (P2a+b2) and modulation sigmoid(P4a+b4)
    float fx = 0.f, fy = 0.f, fm = 0.f;
    if (li < 9) {
        size_t p = (size_t)(b << 12) + hw;
        int c2 = g * 18 + li;
        fx = P2a[p * 80 + c2] + b2[c2];
        fy = P2a[p * 80 + 9 + c2] + b2[9 + c2];
        int c4 = g * 9 + li;
        float mv = P4a[p * 48 + c4] + b4[c4];
        fm = 1.0f / (1.0f + expf(-mv));
    }
    float px = fminf(fmaxf((float)wx + (float)(li % 3 - 1) + fx, 0.f), 63.f);
    float py = fminf(fmaxf((float)hy + (float)(li / 3 - 1) + fy, 0.f), 63.f);
    float x0f = floorf(px), y0f = floorf(py);
    float wxf = px - x0f, wyf = py - y0f;
    int x0 = (int)x0f, y0 = (int)y0f;
    int x1 = min(x0 + 1, 63), y1 = min(y0 + 1, 63);

    // lane li gathers channels g*64 + li*4 .. +3 as float4
    const float4* xb = (const float4*)(x + ((size_t)(b << 12)) * 256 + g * 64 + li * 4);
    float4 acc = make_float4(0.f, 0.f, 0.f, 0.f);
    int sb = sub << 4;
#pragma unroll
    for (int q = 0; q < 9; q++) {
        int src = sb + q;
        int   qx0 = __shfl(x0, src);
        int   qx1 = __shfl(x1, src);
        int   qy0 = __shfl(y0, src);
        int   qy1 = __shfl(y1, src);
        float qwx = __shfl(wxf, src);
        float qwy = __shfl(wyf, src);
        float qm  = __shfl(fm, src);
        float4 v00 = xb[(size_t)(qy0 * 64 + qx0) * 64];
        float4 v01 = xb[(size_t)(qy0 * 64 + qx1) * 64];
        float4 v10 = xb[(size_t)(qy1 * 64 + qx0) * 64];
        float4 v11 = xb[(size_t)(qy1 * 64 + qx1) * 64];
        float w00 = (1.f - qwx) * (1.f - qwy);
        float w01 = qwx * (1.f - qwy);
        float w10 = (1.f - qwx) * qwy;
        float w11 = qwx * qwy;
        acc.x += qm * (v00.x * w00 + v01.x * w01 + v10.x * w10 + v11.x * w11);
        acc.y += qm * (v00.y * w00 + v01.y * w01 + v10.y * w10 + v11.y * w11);
        acc.z += qm * (v00.z * w00 + v01.z * w01 + v10.z * w10 + v11.z * w11);
        acc.w += qm * (v00.w * w00 + v01.w * w01 + v10.w * w10 + v11.w * w11);
    }
    const float s = 1.f / 9.f;
    acc.x *= s; acc.y *= s; acc.z *= s; acc.w *= s;
    float4* ob = (float4*)(out + ((size_t)(b << 12) + hw) * 256 + g * 64 + li * 4);
    *ob = acc;
}

extern "C" void kernel_launch(void* const* d_in, const int* in_sizes, int n_in,
                              void* d_out, int out_size, void* d_ws, size_t ws_size,
                              hipStream_t stream)
{
    const float* x      = (const float*)d_in[0];
    const float* off_w1 = (const float*)d_in[1];
    const float* off_b1 = (const float*)d_in[2];
    const float* off_w2 = (const float*)d_in[3];
    const float* off_b2 = (const float*)d_in[4];
    const float* mod_w1 = (const float*)d_in[5];
    const float* mod_b1 = (const float*)d_in[6];
    const float* mod_w2 = (const float*)d_in[7];
    const float* mod_b2 = (const float*)d_in[8];

    // ws layout (ushort units; split hi/lo arrays, 64B px units)
    const size_t XP = 4u * 4356u * 256u;   // 4,460,544 (8 chunks x 4 b x 4356 x 32)
    const size_t MP = 4u * 4356u * 64u;    // 1,115,136 (2 chunks)
    const size_t W1 = 4u * 2u * 9u * 64u * 32u;  // 147,456
    const size_t W2 = 8u * 9u * 80u * 32u;       // 184,320
    const size_t W3 = 8u * 9u * 64u * 32u;       // 147,456
    const size_t W4 = 2u * 9u * 48u * 32u;       // 27,648

    unsigned short* ws = (unsigned short*)d_ws;
    size_t o = 0;
    unsigned short* xph = ws + o; o += XP;
    unsigned short* xpl = ws + o; o += XP;
    unsigned short* h1h = ws + o; o += XP;
    unsigned short* h1l = ws + o; o += XP;
    unsigned short* m1h = ws + o; o += MP;
    unsigned short* m1l = ws + o; o += MP;
    unsigned short* w1h = ws + o; o += W1;
    unsigned short* w1l = ws + o; o += W1;
    unsigned short* w2h = ws + o; o += W2;
    unsigned short* w2l = ws + o; o += W2;
    unsigned short* w3h = ws + o; o += W3;
    unsigned short* w3l = ws + o; o += W3;
    unsigned short* w4h = ws + o; o += W4;
    unsigned short* w4l = ws + o; o += W4;
    // fp32 accumulators: P3+P2a zeroed by prep seg 0; P4a plain-written (no init)
    float* fbase = (float*)(ws + o);
    float* P3  = fbase;                              // [4*4096][64]
    float* P2a = P3 + (size_t)4 * 4096 * 64;         // [4*4096][80]
    float* P4a = P2a + (size_t)4 * 4096 * 80;        // [4*4096][48]
    const size_t ACC_FLOATS = (size_t)4 * 4096 * (64 + 80 + 48);
    size_t need_bytes = o * 2 + ACC_FLOATS * 4;      // ~55 MB (ws ~268 MB)
    if (ws_size < need_bytes) return;  // deterministic guard

    prep_all_kernel<<<ZBLK + RBLK + XBLK + WBLK, 256, 0, stream>>>(
        x, off_w1, off_w2, mod_w1, mod_w2,
        xph, xpl, h1h, h1l, m1h, m1l,
        w1h, w1l, w2h, w2l, w3h, w3l, w4h, w4l, P3);

    convA_kernel<<<dim3(224, 1, 4), 256, 0, stream>>>(xph, xpl, w1h, w1l, off_b1,
                                                      w3h, w3l, h1h, h1l, P3);
    finalizeA_kernel<<<4096, 256, 0, stream>>>(P3, mod_b1, m1h, m1l);
    convB_kernel<<<dim3(128, 1, 4), 256, 0, stream>>>(h1h, h1l, w2h, w2l,
                                                      m1h, m1l, w4h, w4l, P2a, P4a);
    deform_sample<<<4096, 256, 0, stream>>>(x, P2a, P4a, off_b2, mod_b2, (float*)d_out);
}